// Round 9
// baseline (110.560 us; speedup 1.0000x reference)
//
#include <hip/hip_runtime.h>
#include <hip/hip_bf16.h>

#define N 8192
#define D 192
#define BM 256                      // block rows
#define BN 128                      // block cols
#define BK 32                       // K per phase
#define NKP (D / BK)                // 6 phases
#define NCB (N / BN)                // 64 col-blocks
#define FRAG 1024                   // one MFMA fragment: 64 lanes x 16B
#define AFRAGS (BM / 16)            // 16
#define BFRAGS (BN / 16)            // 8
#define PHASE_BYTES ((AFRAGS + BFRAGS) * FRAG)  // 24576

typedef short short8 __attribute__((ext_vector_type(8)));
typedef float f32x4 __attribute__((ext_vector_type(4)));

#define GLOAD16(gptr, lptr)                                                               \
  __builtin_amdgcn_global_load_lds((const __attribute__((address_space(1))) void*)(gptr), \
                                   (__attribute__((address_space(3))) void*)(lptr), 16, 0, 0)

// ---------------- Kernel 1: row-normalize + diagonal dot (fp32) ----------------
// posn pre-scaled by w*log2e so the GEMM accumulator directly holds the exp2
// argument (c0 offset seeds the accumulator).
__global__ __launch_bounds__(256) void norm_kernel(
    const float* __restrict__ x,
    const float* __restrict__ wp,
    __hip_bfloat16* __restrict__ posn,
    __hip_bfloat16* __restrict__ ancn,
    float* __restrict__ diag) {
  const float c1 = (*wp) * 1.4426950408889634f;
  int gw = (int)((blockIdx.x * 256 + threadIdx.x) >> 6);
  int lane = threadIdx.x & 63;
  if (gw >= N) return;
  const float* row = x + (size_t)gw * (2 * D);
  float p[3], a[3];
  float ssp = 0.f, ssa = 0.f, dt = 0.f;
#pragma unroll
  for (int j = 0; j < 3; ++j) {
    p[j] = row[lane + 64 * j];
    a[j] = row[D + lane + 64 * j];
    ssp += p[j] * p[j];
    ssa += a[j] * a[j];
    dt += p[j] * a[j];
  }
#pragma unroll
  for (int off = 32; off >= 1; off >>= 1) {
    ssp += __shfl_xor(ssp, off, 64);
    ssa += __shfl_xor(ssa, off, 64);
    dt += __shfl_xor(dt, off, 64);
  }
  float invp = 1.f / fmaxf(sqrtf(ssp), 1e-8f);
  float inva = 1.f / fmaxf(sqrtf(ssa), 1e-8f);
#pragma unroll
  for (int j = 0; j < 3; ++j) {
    posn[(size_t)gw * D + lane + 64 * j] = __float2bfloat16(p[j] * invp * c1);
    ancn[(size_t)gw * D + lane + 64 * j] = __float2bfloat16(a[j] * inva);
  }
  if (lane == 0) diag[gw] = dt * invp * inva;
}

// ---------------- Kernel 2: K-accumulating GEMM + fused sum-exp epilogue -------
// m97/m201-proven register shape (the ONLY shape R2-R8 showed this compiler
// handles): per-wave persistent state = acc[8][4] f32x4 = 128 MFMA accumulators
// (AGPR class, compiler-native); A/B input frags are SHORT-LIVED, re-read from
// LDS each K-phase. Block 256x128, 4 waves 2x2, wave-tile 128x64. BK=32,
// 6 phases, double-buffered 24 KB panels (48 KB LDS -> 2 blocks/CU).
// Per wave per phase: 12 ds_read_b128 + 32 MFMA (reuse 5.3 -> MFMA-bound).
// exp2 + row-reduce once, after the full K loop. acc seeded with
// c0 = -|w|*log2e so exp2(acc) is the softmax term directly.
__global__ __launch_bounds__(256) void gemm_lse_kernel(
    const __hip_bfloat16* __restrict__ posn,
    const __hip_bfloat16* __restrict__ ancn,
    const float* __restrict__ wp,
    float* __restrict__ partial) {
  __shared__ char lds[2 * PHASE_BYTES];  // 48 KB

  const int lane = (int)(threadIdx.x & 63);
  const int wv = (int)(threadIdx.x >> 6);
  // Bijective XCD swizzle (2048 = 8 * 256): each XCD covers 4 row-blocks x all
  // 64 col-blocks -> per-XCD L2 footprint ancn 3 MB + 1024 posn rows = 3.4 MB.
  const int sw = (int)((blockIdx.x & 7) * 256 + (blockIdx.x >> 3));
  const int cb = sw & (NCB - 1);
  const int rb = sw >> 6;
  const int rowBase0 = rb * BM;
  const int colBase0 = cb * BN;
  const int wr = wv >> 1;  // wave row (0..1): rows wr*128
  const int wc = wv & 1;   // wave col (0..1): cols wc*64

  const float c0 = -fabsf(*wp) * 1.4426950408889634f;  // (b - M)*log2e, M = |w|+b

  const int r15 = lane & 15;
  const int khi = (lane >> 4) * 8;

  // stage phase p into buffer buf: 24 frags (16 A + 8 B), wave wv stages 6.
  auto stage = [&](int buf, int p) {
    const int kb = p * BK;
    char* l = lds + buf * PHASE_BYTES;
#pragma unroll
    for (int j = 0; j < 6; ++j) {
      const int f = wv * 6 + j;
      const __hip_bfloat16* g =
          (f < AFRAGS)
              ? posn + (size_t)(rowBase0 + f * 16 + r15) * D + kb + khi
              : ancn + (size_t)(colBase0 + (f - AFRAGS) * 16 + r15) * D + kb + khi;
      GLOAD16(g, l + f * FRAG);
    }
  };

  f32x4 acc[8][4];
#pragma unroll
  for (int rs = 0; rs < 8; ++rs)
#pragma unroll
    for (int cs = 0; cs < 4; ++cs) acc[rs][cs] = (f32x4){c0, c0, c0, c0};

  stage(0, 0);
  __syncthreads();

  for (int p = 0; p < NKP; ++p) {
    if (p + 1 < NKP) stage((p + 1) & 1, p + 1);  // prefetch next K-phase
    const char* Ab = lds + (p & 1) * PHASE_BYTES;
    const char* Bb = Ab + AFRAGS * FRAG;
    short8 af[8];
#pragma unroll
    for (int rs = 0; rs < 8; ++rs)
      af[rs] = *(const short8*)(Ab + (wr * 8 + rs) * FRAG + lane * 16);
#pragma unroll
    for (int cs = 0; cs < 4; ++cs) {
      short8 bf = *(const short8*)(Bb + (wc * 4 + cs) * FRAG + lane * 16);
#pragma unroll
      for (int rs = 0; rs < 8; ++rs)
        acc[rs][cs] = __builtin_amdgcn_mfma_f32_16x16x32_bf16(af[rs], bf, acc[rs][cs], 0, 0, 0);
    }
    __syncthreads();  // staging(p+1) complete + all waves done with buf p
  }

  // Epilogue: exp2 over the 128x64 wave tile, reduce over cols.
  float srow[8][4];
#pragma unroll
  for (int rs = 0; rs < 8; ++rs)
#pragma unroll
    for (int r = 0; r < 4; ++r) srow[rs][r] = 0.f;
#pragma unroll
  for (int rs = 0; rs < 8; ++rs)
#pragma unroll
    for (int cs = 0; cs < 4; ++cs)
#pragma unroll
      for (int r = 0; r < 4; ++r)
        srow[rs][r] += __builtin_amdgcn_exp2f(acc[rs][cs][r]);
  // Reduce across the 16 lanes holding the 16 cols of each C tile.
#pragma unroll
  for (int off = 1; off < 16; off <<= 1)
#pragma unroll
    for (int rs = 0; rs < 8; ++rs)
#pragma unroll
      for (int r = 0; r < 4; ++r) srow[rs][r] += __shfl_xor(srow[rs][r], off, 64);

  if (r15 == 0) {
    const int rg = (lane >> 4) * 4;  // C rows: (lane>>4)*4 + r
#pragma unroll
    for (int rs = 0; rs < 8; ++rs)
#pragma unroll
      for (int r = 0; r < 4; ++r)
        partial[(size_t)(cb * 2 + wc) * N + rowBase0 + wr * 128 + rs * 16 + rg + r] =
            srow[rs][r];
  }
}

// ---------------- Kernel 3a: per-row LSE + per-block partial mean ----------------
__global__ __launch_bounds__(256) void finalize1_kernel(
    const float* __restrict__ partial,
    const float* __restrict__ diag,
    const float* __restrict__ wp,
    const float* __restrict__ bp,
    float* __restrict__ blocksum) {
  const float w = *wp, b = *bp;
  const float M = fabsf(w) + b;
  int i = (int)(blockIdx.x * 256 + threadIdx.x);
  float s = 0.f;
#pragma unroll
  for (int c = 0; c < 2 * NCB; ++c) s += partial[(size_t)c * N + i];
  float acc = fmaf(diag[i], w, b) - (M + logf(s));
#pragma unroll
  for (int off = 32; off >= 1; off >>= 1) acc += __shfl_xor(acc, off, 64);
  __shared__ float red[4];
  if ((threadIdx.x & 63) == 0) red[threadIdx.x >> 6] = acc;
  __syncthreads();
  if (threadIdx.x == 0) blocksum[blockIdx.x] = red[0] + red[1] + red[2] + red[3];
}

// ---------------- Kernel 3b: combine 32 block sums -> loss ----------------
__global__ __launch_bounds__(64) void finalize2_kernel(
    const float* __restrict__ blocksum, float* __restrict__ out) {
  int lane = (int)threadIdx.x;
  float v = (lane < 32) ? blocksum[lane] : 0.f;
#pragma unroll
  for (int off = 32; off >= 1; off >>= 1) v += __shfl_xor(v, off, 64);
  if (lane == 0) out[0] = -v / (float)N;
}

extern "C" void kernel_launch(void* const* d_in, const int* in_sizes, int n_in,
                              void* d_out, int out_size, void* d_ws, size_t ws_size,
                              hipStream_t stream) {
  const float* x = (const float*)d_in[0];
  const float* wp = (const float*)d_in[1];
  const float* bp = (const float*)d_in[2];
  float* out = (float*)d_out;

  char* ws = (char*)d_ws;
  __hip_bfloat16* posn = (__hip_bfloat16*)ws;                 // 3,145,728 B
  __hip_bfloat16* ancn = (__hip_bfloat16*)(ws + 3145728);     // 3,145,728 B
  float* diag = (float*)(ws + 6291456);                       // 32,768 B
  float* partial = (float*)(ws + 6324224);                    // 128*8192*4 = 4,194,304 B
  float* blocksum = (float*)(ws + 10518528);                  // 128 B

  norm_kernel<<<N / 4, 256, 0, stream>>>(x, wp, posn, ancn, diag);
  gemm_lse_kernel<<<(N / BM) * NCB, 256, 0, stream>>>(posn, ancn, wp, partial);
  finalize1_kernel<<<N / 256, 256, 0, stream>>>(partial, diag, wp, bp, blocksum);
  finalize2_kernel<<<1, 64, 0, stream>>>(blocksum, out);
}

// Round 10
// 95.138 us; speedup vs baseline: 1.1621x; 1.1621x over previous
//
#include <hip/hip_runtime.h>
#include <hip/hip_bf16.h>

#define N 8192
#define D 192
#define BM 128                      // block rows
#define BN 128                      // block cols
#define BK 32                       // K per phase
#define NKP (D / BK)                // 6 phases
#define NCB (N / BN)                // 64 col-blocks
#define FRAG 1024                   // one MFMA fragment: 64 lanes x 16B
#define AFRAGS (BM / 16)            // 8
#define BFRAGS (BN / 16)            // 8
#define PHASE_BYTES ((AFRAGS + BFRAGS) * FRAG)  // 16384

typedef short short8 __attribute__((ext_vector_type(8)));
typedef float f32x4 __attribute__((ext_vector_type(4)));

#define GLOAD16(gptr, lptr)                                                               \
  __builtin_amdgcn_global_load_lds((const __attribute__((address_space(1))) void*)(gptr), \
                                   (__attribute__((address_space(3))) void*)(lptr), 16, 0, 0)

// ---------------- Kernel 1: row-normalize + diagonal dot (fp32) ----------------
// posn pre-scaled by w*log2e so the GEMM accumulator directly holds the exp2
// argument (c0 offset seeds the accumulator).
__global__ __launch_bounds__(256) void norm_kernel(
    const float* __restrict__ x,
    const float* __restrict__ wp,
    __hip_bfloat16* __restrict__ posn,
    __hip_bfloat16* __restrict__ ancn,
    float* __restrict__ diag) {
  const float c1 = (*wp) * 1.4426950408889634f;
  int gw = (int)((blockIdx.x * 256 + threadIdx.x) >> 6);
  int lane = threadIdx.x & 63;
  if (gw >= N) return;
  const float* row = x + (size_t)gw * (2 * D);
  float p[3], a[3];
  float ssp = 0.f, ssa = 0.f, dt = 0.f;
#pragma unroll
  for (int j = 0; j < 3; ++j) {
    p[j] = row[lane + 64 * j];
    a[j] = row[D + lane + 64 * j];
    ssp += p[j] * p[j];
    ssa += a[j] * a[j];
    dt += p[j] * a[j];
  }
#pragma unroll
  for (int off = 32; off >= 1; off >>= 1) {
    ssp += __shfl_xor(ssp, off, 64);
    ssa += __shfl_xor(ssa, off, 64);
    dt += __shfl_xor(dt, off, 64);
  }
  float invp = 1.f / fmaxf(sqrtf(ssp), 1e-8f);
  float inva = 1.f / fmaxf(sqrtf(ssa), 1e-8f);
#pragma unroll
  for (int j = 0; j < 3; ++j) {
    posn[(size_t)gw * D + lane + 64 * j] = __float2bfloat16(p[j] * invp * c1);
    ancn[(size_t)gw * D + lane + 64 * j] = __float2bfloat16(a[j] * inva);
  }
  if (lane == 0) diag[gw] = dt * invp * inva;
}

// ---------------- Kernel 2: K-accumulating GEMM + fused sum-exp epilogue -------
// R9 post-mortem: wave tile 128x64 -> acc=128 AGPR + 180 VGPR = 308 unified
// regs/wave -> 1 wave/SIMD (Occupancy 10.7%) -> latency-bound at 70 us.
// Fix: wave tile 64x64 -> acc[4][4] f32x4 = 64 regs; target total ~150 ->
// 3 waves/SIMD (waves_per_eu(3,3) pins budget at 170), 3 blocks/CU
// (LDS 32 KB allows 5). Block 128x128, 4 waves 2x2. BK=32, 6 phases fully
// unrolled (all stage/ds offsets become immediates), double-buffered.
// Per wave-phase: 8 ds_read_b128 + 16 MFMA. acc seeded with c0 = -|w|*log2e
// so exp2(acc) is the softmax term directly (M = |w|+b since |dot|<=1).
__global__ __launch_bounds__(256) __attribute__((amdgpu_waves_per_eu(3, 3)))
void gemm_lse_kernel(
    const __hip_bfloat16* __restrict__ posn,
    const __hip_bfloat16* __restrict__ ancn,
    const float* __restrict__ wp,
    float* __restrict__ partial) {
  __shared__ char lds[2 * PHASE_BYTES];  // 32 KB

  const int lane = (int)(threadIdx.x & 63);
  const int wv = (int)(threadIdx.x >> 6);
  // Bijective XCD swizzle (4096 = 8 * 512): each XCD covers 8 row-blocks x all
  // 64 col-blocks -> per-XCD L2 footprint ancn 3 MB + 1024 posn rows = 3.4 MB.
  const int sw = (int)((blockIdx.x & 7) * 512 + (blockIdx.x >> 3));
  const int cb = sw & (NCB - 1);
  const int rb = sw >> 6;
  const int rowBase0 = rb * BM;
  const int colBase0 = cb * BN;
  const int wr = wv >> 1;  // wave row (0..1): rows wr*64
  const int wc = wv & 1;   // wave col (0..1): cols wc*64

  const float c0 = -fabsf(*wp) * 1.4426950408889634f;  // (b - M)*log2e, M = |w|+b

  const int r15 = lane & 15;
  const int khi = (lane >> 4) * 8;

  // Staging assignment: wave 0 -> A frags 0-3, wave 1 -> A frags 4-7,
  // wave 2 -> B frags 0-3 (lds slots 8-11), wave 3 -> B frags 4-7 (slots 12-15).
  const __hip_bfloat16* sbase = (wv < 2) ? posn : ancn;
  const int rcBase = ((wv < 2) ? rowBase0 : colBase0) + (wv & 1) * 64 + r15;
  const int fr0 = ((wv & 2) << 2) + (wv & 1) * 4;  // first lds frag slot
  const __hip_bfloat16* g[4];
#pragma unroll
  for (int j = 0; j < 4; ++j) g[j] = sbase + (size_t)(rcBase + j * 16) * D + khi;

  f32x4 acc[4][4];
#pragma unroll
  for (int rs = 0; rs < 4; ++rs)
#pragma unroll
    for (int cs = 0; cs < 4; ++cs) acc[rs][cs] = (f32x4){c0, c0, c0, c0};

  // Prologue: stage phase 0 into buffer 0.
#pragma unroll
  for (int j = 0; j < 4; ++j) GLOAD16(g[j], lds + (fr0 + j) * FRAG);
  __syncthreads();

#pragma unroll
  for (int p = 0; p < NKP; ++p) {
    if (p + 1 < NKP) {  // prefetch next K-phase into the other buffer
#pragma unroll
      for (int j = 0; j < 4; ++j)
        GLOAD16(g[j] + (p + 1) * BK, lds + ((p + 1) & 1) * PHASE_BYTES + (fr0 + j) * FRAG);
    }
    const char* Ab = lds + (p & 1) * PHASE_BYTES;
    const char* Bb = Ab + AFRAGS * FRAG;
    short8 af[4];
#pragma unroll
    for (int rs = 0; rs < 4; ++rs)
      af[rs] = *(const short8*)(Ab + (wr * 4 + rs) * FRAG + lane * 16);
#pragma unroll
    for (int cs = 0; cs < 4; ++cs) {
      short8 bf = *(const short8*)(Bb + (wc * 4 + cs) * FRAG + lane * 16);
#pragma unroll
      for (int rs = 0; rs < 4; ++rs)
        acc[rs][cs] = __builtin_amdgcn_mfma_f32_16x16x32_bf16(af[rs], bf, acc[rs][cs], 0, 0, 0);
    }
    __syncthreads();  // staging(p+1) complete + all waves done with buf p
  }

  // Epilogue: exp2 over the 64x64 wave tile, reduce over the 64 cols.
  float srow[4][4];
#pragma unroll
  for (int rs = 0; rs < 4; ++rs)
#pragma unroll
    for (int r = 0; r < 4; ++r) srow[rs][r] = 0.f;
#pragma unroll
  for (int rs = 0; rs < 4; ++rs)
#pragma unroll
    for (int cs = 0; cs < 4; ++cs)
#pragma unroll
      for (int r = 0; r < 4; ++r)
        srow[rs][r] += __builtin_amdgcn_exp2f(acc[rs][cs][r]);
  // Reduce across the 16 lanes holding the 16 cols of each C tile.
#pragma unroll
  for (int off = 1; off < 16; off <<= 1)
#pragma unroll
    for (int rs = 0; rs < 4; ++rs)
#pragma unroll
      for (int r = 0; r < 4; ++r) srow[rs][r] += __shfl_xor(srow[rs][r], off, 64);

  if (r15 == 0) {
    const int rg = (lane >> 4) * 4;  // C rows: (lane>>4)*4 + r
#pragma unroll
    for (int rs = 0; rs < 4; ++rs)
#pragma unroll
      for (int r = 0; r < 4; ++r)
        partial[(size_t)(cb * 2 + wc) * N + rowBase0 + wr * 64 + rs * 16 + rg + r] =
            srow[rs][r];
  }
}

// ---------------- Kernel 3a: per-row LSE + per-block partial mean ----------------
__global__ __launch_bounds__(256) void finalize1_kernel(
    const float* __restrict__ partial,
    const float* __restrict__ diag,
    const float* __restrict__ wp,
    const float* __restrict__ bp,
    float* __restrict__ blocksum) {
  const float w = *wp, b = *bp;
  const float M = fabsf(w) + b;
  int i = (int)(blockIdx.x * 256 + threadIdx.x);
  float s = 0.f;
#pragma unroll
  for (int c = 0; c < 2 * NCB; ++c) s += partial[(size_t)c * N + i];
  float acc = fmaf(diag[i], w, b) - (M + logf(s));
#pragma unroll
  for (int off = 32; off >= 1; off >>= 1) acc += __shfl_xor(acc, off, 64);
  __shared__ float red[4];
  if ((threadIdx.x & 63) == 0) red[threadIdx.x >> 6] = acc;
  __syncthreads();
  if (threadIdx.x == 0) blocksum[blockIdx.x] = red[0] + red[1] + red[2] + red[3];
}

// ---------------- Kernel 3b: combine 32 block sums -> loss ----------------
__global__ __launch_bounds__(64) void finalize2_kernel(
    const float* __restrict__ blocksum, float* __restrict__ out) {
  int lane = (int)threadIdx.x;
  float v = (lane < 32) ? blocksum[lane] : 0.f;
#pragma unroll
  for (int off = 32; off >= 1; off >>= 1) v += __shfl_xor(v, off, 64);
  if (lane == 0) out[0] = -v / (float)N;
}

extern "C" void kernel_launch(void* const* d_in, const int* in_sizes, int n_in,
                              void* d_out, int out_size, void* d_ws, size_t ws_size,
                              hipStream_t stream) {
  const float* x = (const float*)d_in[0];
  const float* wp = (const float*)d_in[1];
  const float* bp = (const float*)d_in[2];
  float* out = (float*)d_out;

  char* ws = (char*)d_ws;
  __hip_bfloat16* posn = (__hip_bfloat16*)ws;                 // 3,145,728 B
  __hip_bfloat16* ancn = (__hip_bfloat16*)(ws + 3145728);     // 3,145,728 B
  float* diag = (float*)(ws + 6291456);                       // 32,768 B
  float* partial = (float*)(ws + 6324224);                    // 128*8192*4 = 4,194,304 B
  float* blocksum = (float*)(ws + 10518528);                  // 128 B

  norm_kernel<<<N / 4, 256, 0, stream>>>(x, wp, posn, ancn, diag);
  gemm_lse_kernel<<<(N / BM) * NCB, 256, 0, stream>>>(posn, ancn, wp, partial);
  finalize1_kernel<<<N / 256, 256, 0, stream>>>(partial, diag, wp, bp, blocksum);
  finalize2_kernel<<<1, 64, 0, stream>>>(blocksum, out);
}

// Round 11
// 91.598 us; speedup vs baseline: 1.2070x; 1.0387x over previous
//
#include <hip/hip_runtime.h>
#include <hip/hip_bf16.h>

#define N 8192
#define D 192
#define BM 128                      // block rows
#define BN 256                      // block cols
#define BK 32                       // K per phase
#define NKP (D / BK)                // 6 phases
#define NRB (N / BM)                // 64 row-blocks
#define NCB (N / BN)                // 32 col-blocks
#define FRAG 1024                   // one MFMA fragment: 64 lanes x 16B
#define AFRAGS (BM / 16)            // 8
#define BFRAGS (BN / 16)            // 16
#define PHASE_BYTES ((AFRAGS + BFRAGS) * FRAG)  // 24576

typedef short short8 __attribute__((ext_vector_type(8)));
typedef float f32x4 __attribute__((ext_vector_type(4)));

#define GLOAD16(gptr, lptr)                                                               \
  __builtin_amdgcn_global_load_lds((const __attribute__((address_space(1))) void*)(gptr), \
                                   (__attribute__((address_space(3))) void*)(lptr), 16, 0, 0)

// ---------------- Kernel 1: row-normalize + diagonal dot (fp32) ----------------
// posn pre-scaled by w*log2e so the GEMM accumulator directly holds the exp2
// argument (c0 offset seeds the accumulator).
__global__ __launch_bounds__(256) void norm_kernel(
    const float* __restrict__ x,
    const float* __restrict__ wp,
    __hip_bfloat16* __restrict__ posn,
    __hip_bfloat16* __restrict__ ancn,
    float* __restrict__ diag) {
  const float c1 = (*wp) * 1.4426950408889634f;
  int gw = (int)((blockIdx.x * 256 + threadIdx.x) >> 6);
  int lane = threadIdx.x & 63;
  if (gw >= N) return;
  const float* row = x + (size_t)gw * (2 * D);
  float p[3], a[3];
  float ssp = 0.f, ssa = 0.f, dt = 0.f;
#pragma unroll
  for (int j = 0; j < 3; ++j) {
    p[j] = row[lane + 64 * j];
    a[j] = row[D + lane + 64 * j];
    ssp += p[j] * p[j];
    ssa += a[j] * a[j];
    dt += p[j] * a[j];
  }
#pragma unroll
  for (int off = 32; off >= 1; off >>= 1) {
    ssp += __shfl_xor(ssp, off, 64);
    ssa += __shfl_xor(ssa, off, 64);
    dt += __shfl_xor(dt, off, 64);
  }
  float invp = 1.f / fmaxf(sqrtf(ssp), 1e-8f);
  float inva = 1.f / fmaxf(sqrtf(ssa), 1e-8f);
#pragma unroll
  for (int j = 0; j < 3; ++j) {
    posn[(size_t)gw * D + lane + 64 * j] = __float2bfloat16(p[j] * invp * c1);
    ancn[(size_t)gw * D + lane + 64 * j] = __float2bfloat16(a[j] * inva);
  }
  if (lane == 0) diag[gw] = dt * invp * inva;
}

// ---------------- Kernel 2: K-accumulating GEMM + fused sum-exp epilogue -------
// R10 post-mortem: the register shape (acc[4][4] persistent, short-lived LDS
// operands) compiles clean (VGPR 68, zero spill/remat), but per-phase compute
// (16 MFMA ~ 310 cyc/wave) ~ prefetch latency (~300-500 cyc), so all 6
// vmcnt(0)+barrier drains per block were exposed -> MfmaUtil 17%.
// Fix: SAME per-wave code, wider block: 128x256, 512 threads = 8 waves (2x4 of
// 64x64 tiles). Per phase each SIMD now runs 4 waves x 310 cyc ~ 1240 cyc of
// MFMA against the same ~300 cyc latency -> drain hidden. LDS 24 KB/phase x2.
// waves_per_eu(4,4): budget 128 >> measured ~68-100 pressure, 2 blocks/CU.
__global__ __launch_bounds__(512) __attribute__((amdgpu_waves_per_eu(4, 4)))
void gemm_lse_kernel(
    const __hip_bfloat16* __restrict__ posn,
    const __hip_bfloat16* __restrict__ ancn,
    const float* __restrict__ wp,
    float* __restrict__ partial) {
  __shared__ char lds[2 * PHASE_BYTES];  // 48 KB

  const int lane = (int)(threadIdx.x & 63);
  const int wv = (int)(threadIdx.x >> 6);  // 0..7
  // Bijective XCD swizzle (2048 = 8 * 256): each XCD covers 8 row-blocks x all
  // 32 col-blocks -> per-XCD L2 footprint ancn 3 MB + 1024 posn rows = 3.4 MB.
  const int sw = (int)((blockIdx.x & 7) * 256 + (blockIdx.x >> 3));
  const int cb = sw & (NCB - 1);
  const int rb = sw >> 5;
  const int rowBase0 = rb * BM;
  const int colBase0 = cb * BN;
  const int wr = wv >> 2;  // wave row (0..1): rows wr*64
  const int wc = wv & 3;   // wave col (0..3): cols wc*64

  const float c0 = -fabsf(*wp) * 1.4426950408889634f;  // (b - M)*log2e, M = |w|+b

  const int r15 = lane & 15;
  const int khi = (lane >> 4) * 8;

  // Staging: 24 frags/phase (8 A + 16 B); wave wv stages frags wv*3 .. wv*3+2.
  const __hip_bfloat16* g[3];
#pragma unroll
  for (int j = 0; j < 3; ++j) {
    const int f = wv * 3 + j;
    g[j] = (f < AFRAGS)
               ? posn + (size_t)(rowBase0 + f * 16 + r15) * D + khi
               : ancn + (size_t)(colBase0 + (f - AFRAGS) * 16 + r15) * D + khi;
  }
  const int fr0 = wv * 3;

  f32x4 acc[4][4];
#pragma unroll
  for (int rs = 0; rs < 4; ++rs)
#pragma unroll
    for (int cs = 0; cs < 4; ++cs) acc[rs][cs] = (f32x4){c0, c0, c0, c0};

  // Prologue: stage phase 0 into buffer 0.
#pragma unroll
  for (int j = 0; j < 3; ++j) GLOAD16(g[j], lds + (fr0 + j) * FRAG);
  __syncthreads();

#pragma unroll
  for (int p = 0; p < NKP; ++p) {
    if (p + 1 < NKP) {  // prefetch next K-phase into the other buffer
#pragma unroll
      for (int j = 0; j < 3; ++j)
        GLOAD16(g[j] + (p + 1) * BK, lds + ((p + 1) & 1) * PHASE_BYTES + (fr0 + j) * FRAG);
    }
    const char* Ab = lds + (p & 1) * PHASE_BYTES;
    const char* Bb = Ab + AFRAGS * FRAG;
    short8 af[4];
#pragma unroll
    for (int rs = 0; rs < 4; ++rs)
      af[rs] = *(const short8*)(Ab + (wr * 4 + rs) * FRAG + lane * 16);
#pragma unroll
    for (int cs = 0; cs < 4; ++cs) {
      short8 bf = *(const short8*)(Bb + (wc * 4 + cs) * FRAG + lane * 16);
#pragma unroll
      for (int rs = 0; rs < 4; ++rs)
        acc[rs][cs] = __builtin_amdgcn_mfma_f32_16x16x32_bf16(af[rs], bf, acc[rs][cs], 0, 0, 0);
    }
    if (p + 1 < NKP) __syncthreads();  // staging(p+1) landed + buf p free
  }

  // Epilogue: exp2 over the 64x64 wave tile, reduce over the 64 cols.
  float srow[4][4];
#pragma unroll
  for (int rs = 0; rs < 4; ++rs)
#pragma unroll
    for (int r = 0; r < 4; ++r) srow[rs][r] = 0.f;
#pragma unroll
  for (int rs = 0; rs < 4; ++rs)
#pragma unroll
    for (int cs = 0; cs < 4; ++cs)
#pragma unroll
      for (int r = 0; r < 4; ++r)
        srow[rs][r] += __builtin_amdgcn_exp2f(acc[rs][cs][r]);
  // Reduce across the 16 lanes holding the 16 cols of each C tile.
#pragma unroll
  for (int off = 1; off < 16; off <<= 1)
#pragma unroll
    for (int rs = 0; rs < 4; ++rs)
#pragma unroll
      for (int r = 0; r < 4; ++r) srow[rs][r] += __shfl_xor(srow[rs][r], off, 64);

  if (r15 == 0) {
    const int rg = (lane >> 4) * 4;  // C rows: (lane>>4)*4 + r
#pragma unroll
    for (int rs = 0; rs < 4; ++rs)
#pragma unroll
      for (int r = 0; r < 4; ++r)
        partial[(size_t)(cb * 4 + wc) * N + rowBase0 + wr * 64 + rs * 16 + rg + r] =
            srow[rs][r];
  }
}

// ---------------- Kernel 3a: per-row LSE + per-block partial mean ----------------
__global__ __launch_bounds__(256) void finalize1_kernel(
    const float* __restrict__ partial,
    const float* __restrict__ diag,
    const float* __restrict__ wp,
    const float* __restrict__ bp,
    float* __restrict__ blocksum) {
  const float w = *wp, b = *bp;
  const float M = fabsf(w) + b;
  int i = (int)(blockIdx.x * 256 + threadIdx.x);
  float s = 0.f;
#pragma unroll
  for (int c = 0; c < 4 * NCB; ++c) s += partial[(size_t)c * N + i];
  float acc = fmaf(diag[i], w, b) - (M + logf(s));
#pragma unroll
  for (int off = 32; off >= 1; off >>= 1) acc += __shfl_xor(acc, off, 64);
  __shared__ float red[4];
  if ((threadIdx.x & 63) == 0) red[threadIdx.x >> 6] = acc;
  __syncthreads();
  if (threadIdx.x == 0) blocksum[blockIdx.x] = red[0] + red[1] + red[2] + red[3];
}

// ---------------- Kernel 3b: combine 32 block sums -> loss ----------------
__global__ __launch_bounds__(64) void finalize2_kernel(
    const float* __restrict__ blocksum, float* __restrict__ out) {
  int lane = (int)threadIdx.x;
  float v = (lane < 32) ? blocksum[lane] : 0.f;
#pragma unroll
  for (int off = 32; off >= 1; off >>= 1) v += __shfl_xor(v, off, 64);
  if (lane == 0) out[0] = -v / (float)N;
}

extern "C" void kernel_launch(void* const* d_in, const int* in_sizes, int n_in,
                              void* d_out, int out_size, void* d_ws, size_t ws_size,
                              hipStream_t stream) {
  const float* x = (const float*)d_in[0];
  const float* wp = (const float*)d_in[1];
  const float* bp = (const float*)d_in[2];
  float* out = (float*)d_out;

  char* ws = (char*)d_ws;
  __hip_bfloat16* posn = (__hip_bfloat16*)ws;                 // 3,145,728 B
  __hip_bfloat16* ancn = (__hip_bfloat16*)(ws + 3145728);     // 3,145,728 B
  float* diag = (float*)(ws + 6291456);                       // 32,768 B
  float* partial = (float*)(ws + 6324224);                    // 128*8192*4 = 4,194,304 B
  float* blocksum = (float*)(ws + 10518528);                  // 128 B

  norm_kernel<<<N / 4, 256, 0, stream>>>(x, wp, posn, ancn, diag);
  gemm_lse_kernel<<<NRB * NCB, 512, 0, stream>>>(posn, ancn, wp, partial);
  finalize1_kernel<<<N / 256, 256, 0, stream>>>(partial, diag, wp, bp, blocksum);
  finalize2_kernel<<<1, 64, 0, stream>>>(blocksum, out);
}